// Round 1
// baseline (12700.909 us; speedup 1.0000x reference)
//
#include <hip/hip_runtime.h>
#include <hip/hip_bf16.h>

// Transformer encoder: L=6, D=768, H=12, HD=64, MLP=3072, B=8, N=1024.
// fp32 baseline: LDS-tiled fp32 GEMMs (no fp32 MFMA on CDNA4) + flash attention.
// Residual quirk per reference: residual is h = LN(x) (name shadowing), and the
// SAME ln params are used for both LNs in a block.

#define D_MODEL 768
#define NTOK    8192   // B*N
#define NSEQ    1024
#define NHEAD   12
#define HDIM    64
#define MLPDIM  3072
#define NLAYER  6

// ---------------------------------------------------------------- LayerNorm
__device__ __forceinline__ float block_sum256(float v, float* sbuf) {
#pragma unroll
    for (int o = 32; o > 0; o >>= 1) v += __shfl_down(v, o, 64);
    const int lane = threadIdx.x & 63, w = threadIdx.x >> 6;
    if (lane == 0) sbuf[w] = v;
    __syncthreads();
    float r = sbuf[0] + sbuf[1] + sbuf[2] + sbuf[3];
    __syncthreads();
    return r;
}

__global__ __launch_bounds__(256) void ln_kernel(const float* __restrict__ x,
                                                 const float* __restrict__ g,
                                                 const float* __restrict__ b,
                                                 float* __restrict__ out) {
    __shared__ float sbuf[4];
    const int row = blockIdx.x;
    const int t = threadIdx.x;
    const float* xr = x + (size_t)row * D_MODEL;
    float v0 = xr[t], v1 = xr[t + 256], v2 = xr[t + 512];
    float mean = block_sum256(v0 + v1 + v2, sbuf) * (1.0f / 768.0f);
    float d0 = v0 - mean, d1 = v1 - mean, d2 = v2 - mean;
    float var = block_sum256(d0 * d0 + d1 * d1 + d2 * d2, sbuf) * (1.0f / 768.0f);
    float rs = rsqrtf(var + 1e-5f);
    float* orow = out + (size_t)row * D_MODEL;
    orow[t]       = d0 * rs * g[t]       + b[t];
    orow[t + 256] = d1 * rs * g[t + 256] + b[t + 256];
    orow[t + 512] = d2 * rs * g[t + 512] + b[t + 512];
}

// ---------------------------------------------------------------- GEMM
// C[M,N] = A[M,K] @ B[K,N]  (+ epilogue)
// EPI: 0 = none, 1 = +bias[col] + res[row,col], 2 = gelu(acc + bias[col])
// BN=128, BK=8, 256 threads (16x16), micro-tile TM x 8.
// B-fragment col mapping: cols tx*4..+3 and 64+tx*4..+3 (2-way LDS conflict max).
template <int BM, int EPI>
__global__ __launch_bounds__(256) void gemm_kernel(const float* __restrict__ A,
                                                   const float* __restrict__ B,
                                                   const float* __restrict__ bias,
                                                   const float* __restrict__ res,
                                                   float* __restrict__ C,
                                                   int N, int K) {
    constexpr int BN = 128;
    constexpr int BK = 8;
    constexpr int TM = BM / 16;  // 8 (BM=128) or 4 (BM=64)
    __shared__ float a_lds[BK][BM + 4];
    __shared__ float b_lds[BK][BN];

    const int tid = threadIdx.x;
    const int tx = tid & 15, ty = tid >> 4;
    const int bm = blockIdx.x * BM, bn = blockIdx.y * BN;

    float acc[TM][8] = {};

    const int bk_r = tid >> 5;             // B stage: k row 0..7
    const int bk_c = (tid & 31) * 4;       // B stage: col (float4)

    for (int k0 = 0; k0 < K; k0 += BK) {
        __syncthreads();
        if constexpr (BM == 128) {
            const int ar = tid >> 1, ak = (tid & 1) * 4;
            float4 av = *(const float4*)&A[(size_t)(bm + ar) * K + k0 + ak];
            a_lds[ak + 0][ar] = av.x; a_lds[ak + 1][ar] = av.y;
            a_lds[ak + 2][ar] = av.z; a_lds[ak + 3][ar] = av.w;
        } else {  // BM == 64
            const int ar = tid >> 2, ak = (tid & 3) * 2;
            float2 av = *(const float2*)&A[(size_t)(bm + ar) * K + k0 + ak];
            a_lds[ak + 0][ar] = av.x; a_lds[ak + 1][ar] = av.y;
        }
        *(float4*)&b_lds[bk_r][bk_c] =
            *(const float4*)&B[(size_t)(k0 + bk_r) * N + bn + bk_c];
        __syncthreads();

#pragma unroll
        for (int kk = 0; kk < BK; kk++) {
            float af[TM], bf[8];
#pragma unroll
            for (int i = 0; i < TM; i += 4)
                *(float4*)&af[i] = *(const float4*)&a_lds[kk][ty * TM + i];
            *(float4*)&bf[0] = *(const float4*)&b_lds[kk][tx * 4];
            *(float4*)&bf[4] = *(const float4*)&b_lds[kk][64 + tx * 4];
#pragma unroll
            for (int i = 0; i < TM; i++)
#pragma unroll
                for (int j = 0; j < 8; j++) acc[i][j] += af[i] * bf[j];
        }
    }

    // epilogue
#pragma unroll
    for (int i = 0; i < TM; i++) {
        const int row = bm + ty * TM + i;
#pragma unroll
        for (int half = 0; half < 2; half++) {
            const int colb = bn + half * 64 + tx * 4;
            float4 v;
            float* vp = (float*)&v;
#pragma unroll
            for (int j = 0; j < 4; j++) {
                float a = acc[i][half * 4 + j];
                if constexpr (EPI == 1) {
                    a += bias[colb + j] + res[(size_t)row * N + colb + j];
                } else if constexpr (EPI == 2) {
                    a += bias[colb + j];
                    a = 0.5f * a * (1.0f + erff(a * 0.70710678118654752f));
                }
                vp[j] = a;
            }
            *(float4*)&C[(size_t)row * N + colb] = v;
        }
    }
}

// ---------------------------------------------------------------- Flash attention
// grid: (N/64 q-tiles, B*H). 256 threads (16x16). fp32, online softmax.
// qkv layout: [B, N, 3*H*HD]; q col h*64+c, k at +768, v at +1536.
// Out cols per thread: c = tx + 16*j (bank-conflict-friendly).
__global__ __launch_bounds__(256) void attn_kernel(const float* __restrict__ qkv,
                                                   float* __restrict__ o) {
    constexpr int PAD = 68;
    __shared__ float Qs[64][PAD];
    __shared__ float Ks[64][PAD];
    __shared__ float Vs[64][PAD];

    const int qb = blockIdx.x;   // 0..15
    const int bh = blockIdx.y;   // 0..95
    const int bIdx = bh / NHEAD, hIdx = bh % NHEAD;
    const float* base = qkv + (size_t)bIdx * NSEQ * 2304 + hIdx * HDIM;

    const int tid = threadIdx.x;
    const int tx = tid & 15, ty = tid >> 4;

    // stage Q tile [64 x 64]
    {
        const int r = tid >> 2, c4 = (tid & 3) * 16;
        const float* src = base + (size_t)(qb * 64 + r) * 2304 + c4;
#pragma unroll
        for (int u = 0; u < 4; u++)
            *(float4*)&Qs[r][c4 + 4 * u] = *(const float4*)&src[4 * u];
    }

    float m_[4], l_[4], ov[4][4];
#pragma unroll
    for (int i = 0; i < 4; i++) {
        m_[i] = -1e30f;
        l_[i] = 0.0f;
#pragma unroll
        for (int j = 0; j < 4; j++) ov[i][j] = 0.0f;
    }
    __syncthreads();

    for (int kt = 0; kt < NSEQ / 64; kt++) {
        // stage K,V tiles
        {
            const int r = tid >> 2, c4 = (tid & 3) * 16;
            const float* ksrc = base + 768  + (size_t)(kt * 64 + r) * 2304 + c4;
            const float* vsrc = base + 1536 + (size_t)(kt * 64 + r) * 2304 + c4;
#pragma unroll
            for (int u = 0; u < 4; u++) {
                *(float4*)&Ks[r][c4 + 4 * u] = *(const float4*)&ksrc[4 * u];
                *(float4*)&Vs[r][c4 + 4 * u] = *(const float4*)&vsrc[4 * u];
            }
        }
        __syncthreads();

        // S = (Q K^T) * scale : rows ty*4+i, key cols tx + 16*j
        float s[4][4] = {};
#pragma unroll
        for (int d = 0; d < 64; d += 4) {
            float q_[4][4], k_[4][4];
#pragma unroll
            for (int i = 0; i < 4; i++) {
                float4 t = *(const float4*)&Qs[ty * 4 + i][d];
                q_[i][0] = t.x; q_[i][1] = t.y; q_[i][2] = t.z; q_[i][3] = t.w;
            }
#pragma unroll
            for (int j = 0; j < 4; j++) {
                float4 t = *(const float4*)&Ks[tx + 16 * j][d];
                k_[j][0] = t.x; k_[j][1] = t.y; k_[j][2] = t.z; k_[j][3] = t.w;
            }
#pragma unroll
            for (int i = 0; i < 4; i++)
#pragma unroll
                for (int j = 0; j < 4; j++)
                    s[i][j] += q_[i][0] * k_[j][0] + q_[i][1] * k_[j][1] +
                               q_[i][2] * k_[j][2] + q_[i][3] * k_[j][3];
        }

        // online softmax update (rows shared across the 16 tx lanes)
#pragma unroll
        for (int i = 0; i < 4; i++) {
#pragma unroll
            for (int j = 0; j < 4; j++) s[i][j] *= 0.125f;  // HD^-0.5
            float rm = fmaxf(fmaxf(s[i][0], s[i][1]), fmaxf(s[i][2], s[i][3]));
#pragma unroll
            for (int off = 1; off < 16; off <<= 1) rm = fmaxf(rm, __shfl_xor(rm, off, 64));
            const float mn = fmaxf(m_[i], rm);
            const float sc = __expf(m_[i] - mn);
            float rs = 0.0f;
#pragma unroll
            for (int j = 0; j < 4; j++) {
                float p = __expf(s[i][j] - mn);
                s[i][j] = p;
                rs += p;
            }
#pragma unroll
            for (int off = 1; off < 16; off <<= 1) rs += __shfl_xor(rs, off, 64);
            l_[i] = l_[i] * sc + rs;
            m_[i] = mn;
#pragma unroll
            for (int j = 0; j < 4; j++) ov[i][j] *= sc;
        }

        // O += P @ V ; P row broadcast via shuffles (no LDS round-trip)
#pragma unroll
        for (int kg = 0; kg < 16; kg++) {
            const int srcl = (ty & 3) * 16 + kg;
#pragma unroll
            for (int jj = 0; jj < 4; jj++) {
                const int kpos = kg + 16 * jj;
                float v_[4];
#pragma unroll
                for (int j = 0; j < 4; j++) v_[j] = Vs[kpos][tx + 16 * j];
#pragma unroll
                for (int i = 0; i < 4; i++) {
                    const float p = __shfl(s[i][jj], srcl, 64);
#pragma unroll
                    for (int j = 0; j < 4; j++) ov[i][j] += p * v_[j];
                }
            }
        }
        __syncthreads();
    }

    // write O / l  -> o[b, n, h*64 + c], c = tx + 16*j
    float* obase = o + ((size_t)bIdx * NSEQ + qb * 64) * D_MODEL + hIdx * HDIM;
#pragma unroll
    for (int i = 0; i < 4; i++) {
        const float inv = 1.0f / l_[i];
#pragma unroll
        for (int j = 0; j < 4; j++)
            obase[(size_t)(ty * 4 + i) * D_MODEL + tx + 16 * j] = ov[i][j] * inv;
    }
}

// ---------------------------------------------------------------- driver
extern "C" void kernel_launch(void* const* d_in, const int* in_sizes, int n_in,
                              void* d_out, int out_size, void* d_ws, size_t ws_size,
                              hipStream_t stream) {
    const float* x_in   = (const float*)d_in[0];
    const float* ln_g   = (const float*)d_in[1];
    const float* ln_b   = (const float*)d_in[2];
    const float* w_qkv  = (const float*)d_in[3];
    const float* w_proj = (const float*)d_in[4];
    const float* b_proj = (const float*)d_in[5];
    const float* w1     = (const float*)d_in[6];
    const float* b1     = (const float*)d_in[7];
    const float* w2     = (const float*)d_in[8];
    const float* b2     = (const float*)d_in[9];

    float* xw   = (float*)d_ws;                       // [8192,768]
    float* h    = xw   + (size_t)NTOK * D_MODEL;      // [8192,768]
    float* qkvb = h    + (size_t)NTOK * D_MODEL;      // [8192,2304]
    float* ob   = qkvb + (size_t)NTOK * 3 * D_MODEL;  // [8192,768]
    float* mbuf = qkvb;  // reuse qkv+o region: 8192*2304 + 8192*768 == 8192*3072

    hipMemcpyAsync(xw, x_in, sizeof(float) * (size_t)NTOK * D_MODEL,
                   hipMemcpyDeviceToDevice, stream);

    for (int i = 0; i < NLAYER; i++) {
        const float* g  = ln_g + (size_t)i * D_MODEL;
        const float* bb = ln_b + (size_t)i * D_MODEL;

        // h = LN(x)
        ln_kernel<<<NTOK, 256, 0, stream>>>(xw, g, bb, h);
        // qkv = h @ w_qkv[i]
        gemm_kernel<128, 0><<<dim3(NTOK / 128, 2304 / 128), 256, 0, stream>>>(
            h, w_qkv + (size_t)i * D_MODEL * 2304, nullptr, nullptr, qkvb, 2304, D_MODEL);
        // o = attention(qkv)
        attn_kernel<<<dim3(NSEQ / 64, 8 * NHEAD), 256, 0, stream>>>(qkvb, ob);
        // x = o @ w_proj[i] + b_proj[i] + h
        gemm_kernel<64, 1><<<dim3(NTOK / 64, D_MODEL / 128), 256, 0, stream>>>(
            ob, w_proj + (size_t)i * D_MODEL * D_MODEL, b_proj + (size_t)i * D_MODEL,
            h, xw, D_MODEL, D_MODEL);
        // h = LN(x)
        ln_kernel<<<NTOK, 256, 0, stream>>>(xw, g, bb, h);
        // m = gelu(h @ w1[i] + b1[i])
        gemm_kernel<128, 2><<<dim3(NTOK / 128, MLPDIM / 128), 256, 0, stream>>>(
            h, w1 + (size_t)i * D_MODEL * MLPDIM, b1 + (size_t)i * MLPDIM,
            nullptr, mbuf, MLPDIM, D_MODEL);
        // x = m @ w2[i] + b2[i] + h
        float* outp = (i == NLAYER - 1) ? (float*)d_out : xw;
        gemm_kernel<64, 1><<<dim3(NTOK / 64, D_MODEL / 128), 256, 0, stream>>>(
            mbuf, w2 + (size_t)i * MLPDIM * D_MODEL, b2 + (size_t)i * D_MODEL,
            h, outp, D_MODEL, MLPDIM);
    }
}

// Round 2
// 6387.090 us; speedup vs baseline: 1.9885x; 1.9885x over previous
//
#include <hip/hip_runtime.h>
#include <hip/hip_bf16.h>

// Transformer encoder: L=6, D=768, H=12, HD=64, MLP=3072, B=8, N=1024.
// GEMMs: split-bf16 (hi+lo) 3-MFMA trick on v_mfma_f32_16x16x32_bf16 -> ~fp32 accuracy.
// Attention: fp32 flash kernel (unchanged from R1; next target).
// Residual quirk per reference: residual is h = LN(x); same ln params for both LNs.

#define D_MODEL 768
#define NTOK    8192
#define NSEQ    1024
#define NHEAD   12
#define HDIM    64
#define MLPDIM  3072
#define NLAYER  6

typedef short  short8 __attribute__((ext_vector_type(8)));
typedef ushort us8    __attribute__((ext_vector_type(8)));
typedef float  f32x4  __attribute__((ext_vector_type(4)));

__device__ __forceinline__ ushort f2bf(float f) {
    __hip_bfloat16 h = __float2bfloat16(f);
    ushort u; __builtin_memcpy(&u, &h, 2); return u;
}
__device__ __forceinline__ float bf2f(ushort u) {
    unsigned v = ((unsigned)u) << 16; float f; __builtin_memcpy(&f, &v, 4); return f;
}

#define GLOAD16(gp, lp)                                                        \
    __builtin_amdgcn_global_load_lds(                                          \
        (const __attribute__((address_space(1))) void*)(gp),                   \
        (__attribute__((address_space(3))) void*)(lp), 16, 0, 0)

// ---------------------------------------------------------------- LayerNorm (+ hi/lo split out)
__device__ __forceinline__ float block_sum256(float v, float* sbuf) {
#pragma unroll
    for (int o = 32; o > 0; o >>= 1) v += __shfl_down(v, o, 64);
    const int lane = threadIdx.x & 63, w = threadIdx.x >> 6;
    if (lane == 0) sbuf[w] = v;
    __syncthreads();
    float r = sbuf[0] + sbuf[1] + sbuf[2] + sbuf[3];
    __syncthreads();
    return r;
}

__global__ __launch_bounds__(256) void ln_split_kernel(const float* __restrict__ x,
                                                       const float* __restrict__ g,
                                                       const float* __restrict__ b,
                                                       float* __restrict__ h32,
                                                       ushort* __restrict__ hhi,
                                                       ushort* __restrict__ hlo) {
    __shared__ float xs[768];
    __shared__ float sbuf[4];
    const int row = blockIdx.x, t = threadIdx.x;
    const float* xr = x + (size_t)row * D_MODEL;
    float v0 = xr[t], v1 = xr[t + 256], v2 = xr[t + 512];
    xs[t] = v0; xs[t + 256] = v1; xs[t + 512] = v2;
    float mean = block_sum256(v0 + v1 + v2, sbuf) * (1.0f / 768.0f);
    float d0 = v0 - mean, d1 = v1 - mean, d2 = v2 - mean;
    float var = block_sum256(d0 * d0 + d1 * d1 + d2 * d2, sbuf) * (1.0f / 768.0f);
    float rs = rsqrtf(var + 1e-5f);
    float* hr = h32 + (size_t)row * D_MODEL;
    hr[t]       = d0 * rs * g[t]       + b[t];
    hr[t + 256] = d1 * rs * g[t + 256] + b[t + 256];
    hr[t + 512] = d2 * rs * g[t + 512] + b[t + 512];
    if (t < 96) {
        us8 h8, l8;
#pragma unroll
        for (int e = 0; e < 8; e++) {
            const int k = t * 8 + e;
            float hv = (xs[k] - mean) * rs * g[k] + b[k];
            ushort hb = f2bf(hv);
            h8[e] = hb;
            l8[e] = f2bf(hv - bf2f(hb));
        }
        *(us8*)&hhi[(size_t)row * D_MODEL + t * 8] = h8;
        *(us8*)&hlo[(size_t)row * D_MODEL + t * 8] = l8;
    }
}

// ---------------------------------------------------------------- fp32 -> hi/lo split (elementwise)
__global__ __launch_bounds__(256) void split_kernel(const float* __restrict__ in,
                                                    ushort* __restrict__ hi,
                                                    ushort* __restrict__ lo) {
    const size_t id = (size_t)blockIdx.x * 256 + threadIdx.x;  // one 8-elem chunk
    const float4* p = (const float4*)(in + id * 8);
    float4 a = p[0], c = p[1];
    float v[8] = {a.x, a.y, a.z, a.w, c.x, c.y, c.z, c.w};
    us8 h8, l8;
#pragma unroll
    for (int e = 0; e < 8; e++) {
        ushort hb = f2bf(v[e]);
        h8[e] = hb;
        l8[e] = f2bf(v[e] - bf2f(hb));
    }
    *(us8*)&hi[id * 8] = h8;
    *(us8*)&lo[id * 8] = l8;
}

// ---------------------------------------------------------------- weight pack: fp32[K][N] -> hi/lo [(K/8)][N][8]
__global__ __launch_bounds__(256) void wpack_kernel(const float* __restrict__ w,
                                                    ushort* __restrict__ hi,
                                                    ushort* __restrict__ lo, int N) {
    const int id = blockIdx.x * 256 + threadIdx.x;  // id = kg*N + n
    const int n = id % N, kg = id / N;
    us8 h8, l8;
#pragma unroll
    for (int j = 0; j < 8; j++) {
        float v = w[((size_t)kg * 8 + j) * N + n];
        ushort hb = f2bf(v);
        h8[j] = hb;
        l8[j] = f2bf(v - bf2f(hb));
    }
    *(us8*)&hi[(size_t)id * 8] = h8;
    *(us8*)&lo[(size_t)id * 8] = l8;
}

// ---------------------------------------------------------------- split-bf16 GEMM
// C[M,N] = (Ah+Al)[M,K] @ (Bh+Bl)[K,N], 3 MFMAs: Ah*Bh + Ah*Bl + Al*Bh.
// A: plain row-major bf16 [M][K]; B: packed [(K/8)][N][8].
// Tile 128x128, BK=32, 256 thr = 4 waves (2x2 of 64x64), 16x16x32 MFMA.
// LDS: 4 regions (Ah,Al,Bh,Bl) 8KB each. A slot-swizzle s^=((r>>1)&3) both sides.
// EPI: 0 = fp32 out; 1 = fp32 out + bias[col] + res[row*N+col]; 2 = gelu(.+bias) -> hi/lo bf16.
template <int EPI>
__global__ __launch_bounds__(256) void gemm_split(const ushort* __restrict__ Ah,
                                                  const ushort* __restrict__ Al,
                                                  const ushort* __restrict__ Bh,
                                                  const ushort* __restrict__ Bl,
                                                  const float* __restrict__ bias,
                                                  const float* __restrict__ res,
                                                  float* __restrict__ Cf,
                                                  ushort* __restrict__ Chi,
                                                  ushort* __restrict__ Clo,
                                                  int N, int K) {
    __shared__ ushort lds[4][4096];  // 8KB per region, 32KB total
    const int tid = threadIdx.x;
    const int lane = tid & 63, w = tid >> 6;
    const int bm = blockIdx.x * 128, bn = blockIdx.y * 128;
    const int wm = (w & 1) * 64, wn = (w >> 1) * 64;

    f32x4 acc[4][4];
#pragma unroll
    for (int i = 0; i < 4; i++)
#pragma unroll
        for (int j = 0; j < 4; j++) acc[i][j] = (f32x4){0.f, 0.f, 0.f, 0.f};

    // fragment ds_read offsets (ushort units)
    int a_off[4], b_off[4];
    {
        const int kg = lane >> 4, c = lane & 15;
#pragma unroll
        for (int mi = 0; mi < 4; mi++) {
            const int r = wm + mi * 16 + c;
            const int s = kg ^ ((r >> 1) & 3);
            a_off[mi] = (r * 4 + s) * 8;
        }
#pragma unroll
        for (int nj = 0; nj < 4; nj++) {
            const int n = wn + nj * 16 + c;
            b_off[nj] = (kg * 128 + n) * 8;
        }
    }

    // staging: wave w stages region w (0=Ah,1=Al,2=Bh,3=Bl), 8 x 1KB instrs
    const ushort* src[8];
    if (w < 2) {
        const ushort* As = (w == 0) ? Ah : Al;
#pragma unroll
        for (int i = 0; i < 8; i++) {
            const int r = i * 16 + (lane >> 2);
            const int kq = (lane & 3) ^ ((r >> 1) & 3);
            src[i] = As + (size_t)(bm + r) * K + kq * 8;
        }
    } else {
        const ushort* Bs = (w == 2) ? Bh : Bl;
#pragma unroll
        for (int i = 0; i < 8; i++) {
            const int n = (i & 1) * 64 + lane;
            src[i] = Bs + ((size_t)(i >> 1) * N + bn + n) * 8;
        }
    }
    const size_t sinc = (w < 2) ? (size_t)32 : (size_t)32 * N;

    for (int k0 = 0; k0 < K; k0 += 32) {
        if (k0) __syncthreads();
#pragma unroll
        for (int i = 0; i < 8; i++) {
            GLOAD16(src[i], &lds[w][i * 512]);
            src[i] += sinc;
        }
        __syncthreads();

        short8 ah[4], al[4], bh[4], bl[4];
#pragma unroll
        for (int mi = 0; mi < 4; mi++) {
            ah[mi] = *(const short8*)&lds[0][a_off[mi]];
            al[mi] = *(const short8*)&lds[1][a_off[mi]];
        }
#pragma unroll
        for (int nj = 0; nj < 4; nj++) {
            bh[nj] = *(const short8*)&lds[2][b_off[nj]];
            bl[nj] = *(const short8*)&lds[3][b_off[nj]];
        }
#pragma unroll
        for (int mi = 0; mi < 4; mi++)
#pragma unroll
            for (int nj = 0; nj < 4; nj++) {
                acc[mi][nj] = __builtin_amdgcn_mfma_f32_16x16x32_bf16(ah[mi], bh[nj], acc[mi][nj], 0, 0, 0);
                acc[mi][nj] = __builtin_amdgcn_mfma_f32_16x16x32_bf16(ah[mi], bl[nj], acc[mi][nj], 0, 0, 0);
                acc[mi][nj] = __builtin_amdgcn_mfma_f32_16x16x32_bf16(al[mi], bh[nj], acc[mi][nj], 0, 0, 0);
            }
    }

    // epilogue: C/D layout col=lane&15, row=(lane>>4)*4+reg  [m89-verified]
    const int cc = lane & 15, rb = (lane >> 4) * 4;
#pragma unroll
    for (int mi = 0; mi < 4; mi++) {
#pragma unroll
        for (int nj = 0; nj < 4; nj++) {
            const int col = bn + wn + nj * 16 + cc;
            const int row0 = bm + wm + mi * 16 + rb;
#pragma unroll
            for (int rg = 0; rg < 4; rg++) {
                const int row = row0 + rg;
                float v = acc[mi][nj][rg];
                if constexpr (EPI == 0) {
                    Cf[(size_t)row * N + col] = v;
                } else if constexpr (EPI == 1) {
                    Cf[(size_t)row * N + col] = v + bias[col] + res[(size_t)row * N + col];
                } else {
                    v += bias[col];
                    v = 0.5f * v * (1.0f + erff(v * 0.70710678118654752f));
                    ushort hb = f2bf(v);
                    Chi[(size_t)row * N + col] = hb;
                    Clo[(size_t)row * N + col] = f2bf(v - bf2f(hb));
                }
            }
        }
    }
}

// ---------------------------------------------------------------- Flash attention (fp32, unchanged from R1)
__global__ __launch_bounds__(256) void attn_kernel(const float* __restrict__ qkv,
                                                   float* __restrict__ o) {
    constexpr int PAD = 68;
    __shared__ float Qs[64][PAD];
    __shared__ float Ks[64][PAD];
    __shared__ float Vs[64][PAD];

    const int qb = blockIdx.x;
    const int bh = blockIdx.y;
    const int bIdx = bh / NHEAD, hIdx = bh % NHEAD;
    const float* base = qkv + (size_t)bIdx * NSEQ * 2304 + hIdx * HDIM;

    const int tid = threadIdx.x;
    const int tx = tid & 15, ty = tid >> 4;

    {
        const int r = tid >> 2, c4 = (tid & 3) * 16;
        const float* src = base + (size_t)(qb * 64 + r) * 2304 + c4;
#pragma unroll
        for (int u = 0; u < 4; u++)
            *(float4*)&Qs[r][c4 + 4 * u] = *(const float4*)&src[4 * u];
    }

    float m_[4], l_[4], ov[4][4];
#pragma unroll
    for (int i = 0; i < 4; i++) {
        m_[i] = -1e30f;
        l_[i] = 0.0f;
#pragma unroll
        for (int j = 0; j < 4; j++) ov[i][j] = 0.0f;
    }
    __syncthreads();

    for (int kt = 0; kt < NSEQ / 64; kt++) {
        {
            const int r = tid >> 2, c4 = (tid & 3) * 16;
            const float* ksrc = base + 768  + (size_t)(kt * 64 + r) * 2304 + c4;
            const float* vsrc = base + 1536 + (size_t)(kt * 64 + r) * 2304 + c4;
#pragma unroll
            for (int u = 0; u < 4; u++) {
                *(float4*)&Ks[r][c4 + 4 * u] = *(const float4*)&ksrc[4 * u];
                *(float4*)&Vs[r][c4 + 4 * u] = *(const float4*)&vsrc[4 * u];
            }
        }
        __syncthreads();

        float s[4][4] = {};
#pragma unroll
        for (int d = 0; d < 64; d += 4) {
            float q_[4][4], k_[4][4];
#pragma unroll
            for (int i = 0; i < 4; i++) {
                float4 t = *(const float4*)&Qs[ty * 4 + i][d];
                q_[i][0] = t.x; q_[i][1] = t.y; q_[i][2] = t.z; q_[i][3] = t.w;
            }
#pragma unroll
            for (int j = 0; j < 4; j++) {
                float4 t = *(const float4*)&Ks[tx + 16 * j][d];
                k_[j][0] = t.x; k_[j][1] = t.y; k_[j][2] = t.z; k_[j][3] = t.w;
            }
#pragma unroll
            for (int i = 0; i < 4; i++)
#pragma unroll
                for (int j = 0; j < 4; j++)
                    s[i][j] += q_[i][0] * k_[j][0] + q_[i][1] * k_[j][1] +
                               q_[i][2] * k_[j][2] + q_[i][3] * k_[j][3];
        }

#pragma unroll
        for (int i = 0; i < 4; i++) {
#pragma unroll
            for (int j = 0; j < 4; j++) s[i][j] *= 0.125f;
            float rm = fmaxf(fmaxf(s[i][0], s[i][1]), fmaxf(s[i][2], s[i][3]));
#pragma unroll
            for (int off = 1; off < 16; off <<= 1) rm = fmaxf(rm, __shfl_xor(rm, off, 64));
            const float mn = fmaxf(m_[i], rm);
            const float sc = __expf(m_[i] - mn);
            float rs = 0.0f;
#pragma unroll
            for (int j = 0; j < 4; j++) {
                float p = __expf(s[i][j] - mn);
                s[i][j] = p;
                rs += p;
            }
#pragma unroll
            for (int off = 1; off < 16; off <<= 1) rs += __shfl_xor(rs, off, 64);
            l_[i] = l_[i] * sc + rs;
            m_[i] = mn;
#pragma unroll
            for (int j = 0; j < 4; j++) ov[i][j] *= sc;
        }

#pragma unroll
        for (int kg = 0; kg < 16; kg++) {
            const int srcl = (ty & 3) * 16 + kg;
#pragma unroll
            for (int jj = 0; jj < 4; jj++) {
                const int kpos = kg + 16 * jj;
                float v_[4];
#pragma unroll
                for (int j = 0; j < 4; j++) v_[j] = Vs[kpos][tx + 16 * j];
#pragma unroll
                for (int i = 0; i < 4; i++) {
                    const float p = __shfl(s[i][jj], srcl, 64);
#pragma unroll
                    for (int j = 0; j < 4; j++) ov[i][j] += p * v_[j];
                }
            }
        }
        __syncthreads();
    }

    float* obase = o + ((size_t)bIdx * NSEQ + qb * 64) * D_MODEL + hIdx * HDIM;
#pragma unroll
    for (int i = 0; i < 4; i++) {
        const float inv = 1.0f / l_[i];
#pragma unroll
        for (int j = 0; j < 4; j++)
            obase[(size_t)(ty * 4 + i) * D_MODEL + tx + 16 * j] = ov[i][j] * inv;
    }
}

// ---------------------------------------------------------------- driver
extern "C" void kernel_launch(void* const* d_in, const int* in_sizes, int n_in,
                              void* d_out, int out_size, void* d_ws, size_t ws_size,
                              hipStream_t stream) {
    const float* x_in   = (const float*)d_in[0];
    const float* ln_g   = (const float*)d_in[1];
    const float* ln_b   = (const float*)d_in[2];
    const float* w_qkv  = (const float*)d_in[3];
    const float* w_proj = (const float*)d_in[4];
    const float* b_proj = (const float*)d_in[5];
    const float* w1     = (const float*)d_in[6];
    const float* b1     = (const float*)d_in[7];
    const float* w2     = (const float*)d_in[8];
    const float* b2     = (const float*)d_in[9];

    const size_t SZ_X = (size_t)NTOK * D_MODEL;           // 6291456
    const size_t SZ_QKV = (size_t)NTOK * 3 * D_MODEL;     // 18874368
    const size_t WQ = (size_t)D_MODEL * 2304, WP = (size_t)D_MODEL * D_MODEL;
    const size_t W1S = (size_t)D_MODEL * MLPDIM, W2S = (size_t)MLPDIM * D_MODEL;

    char* p = (char*)d_ws;
    float* xw  = (float*)p;  p += SZ_X * 4;
    float* h   = (float*)p;  p += SZ_X * 4;
    ushort* hhi = (ushort*)p; p += SZ_X * 2;
    ushort* hlo = (ushort*)p; p += SZ_X * 2;
    float* qkv = (float*)p;  p += SZ_QKV * 4;
    float* ob  = (float*)p;  p += SZ_X * 4;
    ushort* ohi = (ushort*)p; p += SZ_X * 2;
    ushort* olo = (ushort*)p; p += SZ_X * 2;
    ushort* wqh = (ushort*)p; p += WQ * 2;
    ushort* wql = (ushort*)p; p += WQ * 2;
    ushort* wph = (ushort*)p; p += WP * 2;
    ushort* wpl = (ushort*)p; p += WP * 2;
    ushort* w1h = (ushort*)p; p += W1S * 2;
    ushort* w1l = (ushort*)p; p += W1S * 2;
    ushort* w2h = (ushort*)p; p += W2S * 2;
    ushort* w2l = (ushort*)p; p += W2S * 2;
    ushort* mhi = (ushort*)qkv;                  // alias qkv+ob (dead when MLP runs)
    ushort* mlo = mhi + (size_t)NTOK * MLPDIM;

    for (int i = 0; i < NLAYER; i++) {
        const float* g  = ln_g + (size_t)i * D_MODEL;
        const float* bb = ln_b + (size_t)i * D_MODEL;

        wpack_kernel<<<(96 * 2304) / 256, 256, 0, stream>>>(w_qkv + i * WQ, wqh, wql, 2304);
        wpack_kernel<<<(96 * 768) / 256, 256, 0, stream>>>(w_proj + i * WP, wph, wpl, 768);
        wpack_kernel<<<(96 * 3072) / 256, 256, 0, stream>>>(w1 + i * W1S, w1h, w1l, 3072);
        wpack_kernel<<<(384 * 768) / 256, 256, 0, stream>>>(w2 + i * W2S, w2h, w2l, 768);

        ln_split_kernel<<<NTOK, 256, 0, stream>>>(i == 0 ? x_in : xw, g, bb, h, hhi, hlo);

        gemm_split<0><<<dim3(64, 18), 256, 0, stream>>>(hhi, hlo, wqh, wql, nullptr, nullptr,
                                                        qkv, nullptr, nullptr, 2304, 768);

        attn_kernel<<<dim3(NSEQ / 64, 8 * NHEAD), 256, 0, stream>>>(qkv, ob);

        split_kernel<<<(int)(SZ_X / 8 / 256), 256, 0, stream>>>(ob, ohi, olo);

        gemm_split<1><<<dim3(64, 6), 256, 0, stream>>>(ohi, olo, wph, wpl,
                                                       b_proj + (size_t)i * D_MODEL, h,
                                                       xw, nullptr, nullptr, 768, 768);

        ln_split_kernel<<<NTOK, 256, 0, stream>>>(xw, g, bb, h, hhi, hlo);

        gemm_split<2><<<dim3(64, 24), 256, 0, stream>>>(hhi, hlo, w1h, w1l,
                                                        b1 + (size_t)i * MLPDIM, nullptr,
                                                        nullptr, mhi, mlo, 3072, 768);

        float* outp = (i == NLAYER - 1) ? (float*)d_out : xw;
        gemm_split<1><<<dim3(64, 6), 256, 0, stream>>>(mhi, mlo, w2h, w2l,
                                                       b2 + (size_t)i * D_MODEL, h,
                                                       outp, nullptr, nullptr, 768, 3072);
    }
}

// Round 7
// 3403.139 us; speedup vs baseline: 3.7321x; 1.8768x over previous
//
#include <hip/hip_runtime.h>
#include <hip/hip_bf16.h>

// Transformer encoder: L=6, D=768, H=12, HD=64, MLP=3072, B=8, N=1024.
// GEMMs: split-bf16 (hi+lo) 3-MFMA trick on v_mfma_f32_16x16x32_bf16.
// Attention: MFMA flash kernel, swapped QK^T (S^T), split-bf16 Q/K, bf16 P/V,
//            fused hi/lo split epilogue.
// R4: fix attn epilogue row index (was missing bIdx*NSEQ -> batches raced into
//     rows 0..1023 and tokens >=1024 read poison; absmax 0.639).
// R5/R6/R7: identical resubmits (R4-R6 infra failures, kernel never ran).

#define D_MODEL 768
#define NTOK    8192
#define NSEQ    1024
#define NHEAD   12
#define HDIM    64
#define MLPDIM  3072
#define NLAYER  6

typedef short  short8 __attribute__((ext_vector_type(8)));
typedef ushort us8    __attribute__((ext_vector_type(8)));
typedef ushort us4    __attribute__((ext_vector_type(4)));
typedef float  f32x4  __attribute__((ext_vector_type(4)));

__device__ __forceinline__ ushort f2bf(float f) {
    __hip_bfloat16 h = __float2bfloat16(f);
    ushort u; __builtin_memcpy(&u, &h, 2); return u;
}
__device__ __forceinline__ float bf2f(ushort u) {
    unsigned v = ((unsigned)u) << 16; float f; __builtin_memcpy(&f, &v, 4); return f;
}

#define GLOAD16(gp, lp)                                                        \
    __builtin_amdgcn_global_load_lds(                                          \
        (const __attribute__((address_space(1))) void*)(gp),                   \
        (__attribute__((address_space(3))) void*)(lp), 16, 0, 0)

// ---------------------------------------------------------------- LayerNorm (+ hi/lo split out)
__device__ __forceinline__ float block_sum256(float v, float* sbuf) {
#pragma unroll
    for (int o = 32; o > 0; o >>= 1) v += __shfl_down(v, o, 64);
    const int lane = threadIdx.x & 63, w = threadIdx.x >> 6;
    if (lane == 0) sbuf[w] = v;
    __syncthreads();
    float r = sbuf[0] + sbuf[1] + sbuf[2] + sbuf[3];
    __syncthreads();
    return r;
}

__global__ __launch_bounds__(256) void ln_split_kernel(const float* __restrict__ x,
                                                       const float* __restrict__ g,
                                                       const float* __restrict__ b,
                                                       float* __restrict__ h32,
                                                       ushort* __restrict__ hhi,
                                                       ushort* __restrict__ hlo) {
    __shared__ float xs[768];
    __shared__ float sbuf[4];
    const int row = blockIdx.x, t = threadIdx.x;
    const float* xr = x + (size_t)row * D_MODEL;
    float v0 = xr[t], v1 = xr[t + 256], v2 = xr[t + 512];
    xs[t] = v0; xs[t + 256] = v1; xs[t + 512] = v2;
    float mean = block_sum256(v0 + v1 + v2, sbuf) * (1.0f / 768.0f);
    float d0 = v0 - mean, d1 = v1 - mean, d2 = v2 - mean;
    float var = block_sum256(d0 * d0 + d1 * d1 + d2 * d2, sbuf) * (1.0f / 768.0f);
    float rs = rsqrtf(var + 1e-5f);
    float* hr = h32 + (size_t)row * D_MODEL;
    hr[t]       = d0 * rs * g[t]       + b[t];
    hr[t + 256] = d1 * rs * g[t + 256] + b[t + 256];
    hr[t + 512] = d2 * rs * g[t + 512] + b[t + 512];
    if (t < 96) {
        us8 h8, l8;
#pragma unroll
        for (int e = 0; e < 8; e++) {
            const int k = t * 8 + e;
            float hv = (xs[k] - mean) * rs * g[k] + b[k];
            ushort hb = f2bf(hv);
            h8[e] = hb;
            l8[e] = f2bf(hv - bf2f(hb));
        }
        *(us8*)&hhi[(size_t)row * D_MODEL + t * 8] = h8;
        *(us8*)&hlo[(size_t)row * D_MODEL + t * 8] = l8;
    }
}

// ---------------------------------------------------------------- weight pack: fp32[K][N] -> hi/lo [(K/8)][N][8]
__global__ __launch_bounds__(256) void wpack_kernel(const float* __restrict__ w,
                                                    ushort* __restrict__ hi,
                                                    ushort* __restrict__ lo, int N) {
    const int id = blockIdx.x * 256 + threadIdx.x;
    const int n = id % N, kg = id / N;
    us8 h8, l8;
#pragma unroll
    for (int j = 0; j < 8; j++) {
        float v = w[((size_t)kg * 8 + j) * N + n];
        ushort hb = f2bf(v);
        h8[j] = hb;
        l8[j] = f2bf(v - bf2f(hb));
    }
    *(us8*)&hi[(size_t)id * 8] = h8;
    *(us8*)&lo[(size_t)id * 8] = l8;
}

// ---------------------------------------------------------------- split-bf16 GEMM
template <int EPI>
__global__ __launch_bounds__(256) void gemm_split(const ushort* __restrict__ Ah,
                                                  const ushort* __restrict__ Al,
                                                  const ushort* __restrict__ Bh,
                                                  const ushort* __restrict__ Bl,
                                                  const float* __restrict__ bias,
                                                  const float* __restrict__ res,
                                                  float* __restrict__ Cf,
                                                  ushort* __restrict__ Chi,
                                                  ushort* __restrict__ Clo,
                                                  int N, int K) {
    __shared__ ushort lds[4][4096];
    const int tid = threadIdx.x;
    const int lane = tid & 63, w = tid >> 6;
    const int bm = blockIdx.x * 128, bn = blockIdx.y * 128;
    const int wm = (w & 1) * 64, wn = (w >> 1) * 64;

    f32x4 acc[4][4];
#pragma unroll
    for (int i = 0; i < 4; i++)
#pragma unroll
        for (int j = 0; j < 4; j++) acc[i][j] = (f32x4){0.f, 0.f, 0.f, 0.f};

    int a_off[4], b_off[4];
    {
        const int kg = lane >> 4, c = lane & 15;
#pragma unroll
        for (int mi = 0; mi < 4; mi++) {
            const int r = wm + mi * 16 + c;
            const int s = kg ^ ((r >> 1) & 3);
            a_off[mi] = (r * 4 + s) * 8;
        }
#pragma unroll
        for (int nj = 0; nj < 4; nj++) {
            const int n = wn + nj * 16 + c;
            b_off[nj] = (kg * 128 + n) * 8;
        }
    }

    const ushort* src[8];
    if (w < 2) {
        const ushort* As = (w == 0) ? Ah : Al;
#pragma unroll
        for (int i = 0; i < 8; i++) {
            const int r = i * 16 + (lane >> 2);
            const int kq = (lane & 3) ^ ((r >> 1) & 3);
            src[i] = As + (size_t)(bm + r) * K + kq * 8;
        }
    } else {
        const ushort* Bs = (w == 2) ? Bh : Bl;
#pragma unroll
        for (int i = 0; i < 8; i++) {
            const int n = (i & 1) * 64 + lane;
            src[i] = Bs + ((size_t)(i >> 1) * N + bn + n) * 8;
        }
    }
    const size_t sinc = (w < 2) ? (size_t)32 : (size_t)32 * N;

    for (int k0 = 0; k0 < K; k0 += 32) {
        if (k0) __syncthreads();
#pragma unroll
        for (int i = 0; i < 8; i++) {
            GLOAD16(src[i], &lds[w][i * 512]);
            src[i] += sinc;
        }
        __syncthreads();

        short8 ah[4], al[4], bh[4], bl[4];
#pragma unroll
        for (int mi = 0; mi < 4; mi++) {
            ah[mi] = *(const short8*)&lds[0][a_off[mi]];
            al[mi] = *(const short8*)&lds[1][a_off[mi]];
        }
#pragma unroll
        for (int nj = 0; nj < 4; nj++) {
            bh[nj] = *(const short8*)&lds[2][b_off[nj]];
            bl[nj] = *(const short8*)&lds[3][b_off[nj]];
        }
#pragma unroll
        for (int mi = 0; mi < 4; mi++)
#pragma unroll
            for (int nj = 0; nj < 4; nj++) {
                acc[mi][nj] = __builtin_amdgcn_mfma_f32_16x16x32_bf16(ah[mi], bh[nj], acc[mi][nj], 0, 0, 0);
                acc[mi][nj] = __builtin_amdgcn_mfma_f32_16x16x32_bf16(ah[mi], bl[nj], acc[mi][nj], 0, 0, 0);
                acc[mi][nj] = __builtin_amdgcn_mfma_f32_16x16x32_bf16(al[mi], bh[nj], acc[mi][nj], 0, 0, 0);
            }
    }

    const int cc = lane & 15, rb = (lane >> 4) * 4;
#pragma unroll
    for (int mi = 0; mi < 4; mi++) {
#pragma unroll
        for (int nj = 0; nj < 4; nj++) {
            const int col = bn + wn + nj * 16 + cc;
            const int row0 = bm + wm + mi * 16 + rb;
#pragma unroll
            for (int rg = 0; rg < 4; rg++) {
                const int row = row0 + rg;
                float v = acc[mi][nj][rg];
                if constexpr (EPI == 0) {
                    Cf[(size_t)row * N + col] = v;
                } else if constexpr (EPI == 1) {
                    Cf[(size_t)row * N + col] = v + bias[col] + res[(size_t)row * N + col];
                } else {
                    v += bias[col];
                    v = 0.5f * v * (1.0f + erff(v * 0.70710678118654752f));
                    ushort hb = f2bf(v);
                    Chi[(size_t)row * N + col] = hb;
                    Clo[(size_t)row * N + col] = f2bf(v - bf2f(hb));
                }
            }
        }
    }
}

// ---------------------------------------------------------------- MFMA flash attention
__global__ __launch_bounds__(256) void attn_kernel(const float* __restrict__ qkv,
                                                   ushort* __restrict__ ohi,
                                                   ushort* __restrict__ olo) {
    __shared__ ushort KhL[4096];
    __shared__ ushort KlL[4096];
    __shared__ ushort VtL[4096];
    __shared__ ushort PL[4][1280];  // per-wave, stride 80 per q row

    const int qb = blockIdx.x;
    const int bh = blockIdx.y;
    const int bIdx = bh / NHEAD, hIdx = bh % NHEAD;
    const float* base = qkv + (size_t)bIdx * NSEQ * 2304 + hIdx * HDIM;

    const int tid = threadIdx.x;
    const int lane = tid & 63, w = tid >> 6;
    const int g = lane >> 4, qq = lane & 15;

    // ---- hoist Q fragments (scaled by HD^-0.5, split hi/lo)
    short8 qh[2], ql[2];
    {
        const float* qrow = base + (size_t)(qb * 64 + w * 16 + qq) * 2304;
#pragma unroll
        for (int dc = 0; dc < 2; dc++) {
            float qv[8];
            *(float4*)&qv[0] = *(const float4*)(qrow + dc * 32 + g * 8);
            *(float4*)&qv[4] = *(const float4*)(qrow + dc * 32 + g * 8 + 4);
            us8 h8, l8;
#pragma unroll
            for (int e = 0; e < 8; e++) {
                float v = qv[e] * 0.125f;
                ushort hb = f2bf(v);
                h8[e] = hb;
                l8[e] = f2bf(v - bf2f(hb));
            }
            qh[dc] = (short8)h8;
            ql[dc] = (short8)l8;
        }
    }

    float m_r = -1e30f, l_r = 0.0f;
    f32x4 ot[4];
#pragma unroll
    for (int i = 0; i < 4; i++) ot[i] = (f32x4){0.f, 0.f, 0.f, 0.f};

    const int skey = tid & 63, sdb = tid >> 6;
    const int k7s = (skey & 7) << 4;
    char* KhC = (char*)KhL; char* KlC = (char*)KlL; char* VtC = (char*)VtL;
    char* PLw = (char*)PL[w];

    for (int kt = 0; kt < 16; kt++) {
        __syncthreads();
        // ---- stage K (hi/lo)
        {
            const float* krow = base + 768 + (size_t)(kt * 64 + skey) * 2304 + sdb * 16;
            float kv[16];
            *(float4*)&kv[0]  = *(const float4*)(krow + 0);
            *(float4*)&kv[4]  = *(const float4*)(krow + 4);
            *(float4*)&kv[8]  = *(const float4*)(krow + 8);
            *(float4*)&kv[12] = *(const float4*)(krow + 12);
#pragma unroll
            for (int u = 0; u < 2; u++) {
                us8 h8, l8;
#pragma unroll
                for (int e = 0; e < 8; e++) {
                    float v = kv[u * 8 + e];
                    ushort hb = f2bf(v);
                    h8[e] = hb;
                    l8[e] = f2bf(v - bf2f(hb));
                }
                const int off = skey * 128 + ((sdb * 32 + u * 16) ^ k7s);
                *(us8*)(KhC + off) = h8;
                *(us8*)(KlC + off) = l8;
            }
        }
        // ---- stage V transposed
        {
            const float* vrow = base + 1536 + (size_t)(kt * 64 + skey) * 2304 + sdb * 16;
            float vv[16];
            *(float4*)&vv[0]  = *(const float4*)(vrow + 0);
            *(float4*)&vv[4]  = *(const float4*)(vrow + 4);
            *(float4*)&vv[8]  = *(const float4*)(vrow + 8);
            *(float4*)&vv[12] = *(const float4*)(vrow + 12);
#pragma unroll
            for (int j = 0; j < 16; j++) {
                const int d = sdb * 16 + j;
                const int off = d * 128 + ((skey * 2) ^ ((d & 7) << 4));
                *(ushort*)(VtC + off) = f2bf(vv[j]);
            }
        }
        __syncthreads();

        // ---- S^T = K @ Q
        f32x4 st[4];
#pragma unroll
        for (int s = 0; s < 4; s++) {
            const int row = s * 16 + qq;
            const int sw = (row & 7) << 4;
            const int ab0 = row * 128 + ((g * 16) ^ sw);
            const int ab1 = row * 128 + ((64 + g * 16) ^ sw);
            short8 ah0 = *(const short8*)(KhC + ab0);
            short8 ah1 = *(const short8*)(KhC + ab1);
            short8 al0 = *(const short8*)(KlC + ab0);
            short8 al1 = *(const short8*)(KlC + ab1);
            f32x4 a = (f32x4){0.f, 0.f, 0.f, 0.f};
            a = __builtin_amdgcn_mfma_f32_16x16x32_bf16(ah0, qh[0], a, 0, 0, 0);
            a = __builtin_amdgcn_mfma_f32_16x16x32_bf16(ah1, qh[1], a, 0, 0, 0);
            a = __builtin_amdgcn_mfma_f32_16x16x32_bf16(ah0, ql[0], a, 0, 0, 0);
            a = __builtin_amdgcn_mfma_f32_16x16x32_bf16(ah1, ql[1], a, 0, 0, 0);
            a = __builtin_amdgcn_mfma_f32_16x16x32_bf16(al0, qh[0], a, 0, 0, 0);
            a = __builtin_amdgcn_mfma_f32_16x16x32_bf16(al1, qh[1], a, 0, 0, 0);
            st[s] = a;
        }

        // ---- online softmax
        float rm = -1e30f;
#pragma unroll
        for (int s = 0; s < 4; s++)
#pragma unroll
            for (int j = 0; j < 4; j++) rm = fmaxf(rm, st[s][j]);
        rm = fmaxf(rm, __shfl_xor(rm, 16, 64));
        rm = fmaxf(rm, __shfl_xor(rm, 32, 64));
        const float mn = fmaxf(m_r, rm);
        const float sc = __expf(m_r - mn);
        float rs = 0.0f;
#pragma unroll
        for (int s = 0; s < 4; s++)
#pragma unroll
            for (int j = 0; j < 4; j++) {
                float p = __expf(st[s][j] - mn);
                st[s][j] = p;
                rs += p;
            }
        rs += __shfl_xor(rs, 16, 64);
        rs += __shfl_xor(rs, 32, 64);
        l_r = l_r * sc + rs;
        m_r = mn;
#pragma unroll
        for (int i = 0; i < 4; i++)
#pragma unroll
            for (int j = 0; j < 4; j++) ot[i][j] *= sc;

        // ---- P -> LDS (wave-private)
#pragma unroll
        for (int s = 0; s < 4; s++) {
            us4 p4;
#pragma unroll
            for (int j = 0; j < 4; j++) p4[j] = f2bf(st[s][j]);
            *(us4*)(PLw + qq * 160 + s * 32 + g * 8) = p4;
        }

        // ---- O^T += V^T @ P
        short8 pb0 = *(const short8*)(PLw + qq * 160 + g * 16);
        short8 pb1 = *(const short8*)(PLw + qq * 160 + 64 + g * 16);
#pragma unroll
        for (int ds = 0; ds < 4; ds++) {
            const int row = ds * 16 + qq;
            const int sw = (row & 7) << 4;
            short8 va0 = *(const short8*)(VtC + row * 128 + ((g * 16) ^ sw));
            short8 va1 = *(const short8*)(VtC + row * 128 + ((64 + g * 16) ^ sw));
            ot[ds] = __builtin_amdgcn_mfma_f32_16x16x32_bf16(va0, pb0, ot[ds], 0, 0, 0);
            ot[ds] = __builtin_amdgcn_mfma_f32_16x16x32_bf16(va1, pb1, ot[ds], 0, 0, 0);
        }
    }

    // ---- epilogue: O[q][dout] = Ot[dout][q]/l, write hi/lo bf16
    const float inv = 1.0f / l_r;
    const size_t orow = (size_t)bIdx * NSEQ + qb * 64 + w * 16 + qq;  // R4 FIX: += bIdx*NSEQ
#pragma unroll
    for (int ds = 0; ds < 4; ds++) {
        const int colb = hIdx * 64 + ds * 16 + g * 4;
        us4 h4, l4;
#pragma unroll
        for (int rg = 0; rg < 4; rg++) {
            float v = ot[ds][rg] * inv;
            ushort hb = f2bf(v);
            h4[rg] = hb;
            l4[rg] = f2bf(v - bf2f(hb));
        }
        *(us4*)&ohi[orow * D_MODEL + colb] = h4;
        *(us4*)&olo[orow * D_MODEL + colb] = l4;
    }
}

// ---------------------------------------------------------------- driver
extern "C" void kernel_launch(void* const* d_in, const int* in_sizes, int n_in,
                              void* d_out, int out_size, void* d_ws, size_t ws_size,
                              hipStream_t stream) {
    const float* x_in   = (const float*)d_in[0];
    const float* ln_g   = (const float*)d_in[1];
    const float* ln_b   = (const float*)d_in[2];
    const float* w_qkv  = (const float*)d_in[3];
    const float* w_proj = (const float*)d_in[4];
    const float* b_proj = (const float*)d_in[5];
    const float* w1     = (const float*)d_in[6];
    const float* b1     = (const float*)d_in[7];
    const float* w2     = (const float*)d_in[8];
    const float* b2     = (const float*)d_in[9];

    const size_t SZ_X = (size_t)NTOK * D_MODEL;
    const size_t SZ_QKV = (size_t)NTOK * 3 * D_MODEL;
    const size_t WQ = (size_t)D_MODEL * 2304, WP = (size_t)D_MODEL * D_MODEL;
    const size_t W1S = (size_t)D_MODEL * MLPDIM, W2S = (size_t)MLPDIM * D_MODEL;

    char* p = (char*)d_ws;
    float* xw  = (float*)p;  p += SZ_X * 4;
    float* h   = (float*)p;  p += SZ_X * 4;
    ushort* hhi = (ushort*)p; p += SZ_X * 2;
    ushort* hlo = (ushort*)p; p += SZ_X * 2;
    float* qkv = (float*)p;  p += SZ_QKV * 4;
    ushort* ohi = (ushort*)p; p += SZ_X * 2;
    ushort* olo = (ushort*)p; p += SZ_X * 2;
    ushort* wqh = (ushort*)p; p += WQ * 2;
    ushort* wql = (ushort*)p; p += WQ * 2;
    ushort* wph = (ushort*)p; p += WP * 2;
    ushort* wpl = (ushort*)p; p += WP * 2;
    ushort* w1h = (ushort*)p; p += W1S * 2;
    ushort* w1l = (ushort*)p; p += W1S * 2;
    ushort* w2h = (ushort*)p; p += W2S * 2;
    ushort* w2l = (ushort*)p; p += W2S * 2;
    ushort* mhi = (ushort*)qkv;                  // alias qkv+ohi+olo (dead when MLP runs)
    ushort* mlo = mhi + (size_t)NTOK * MLPDIM;

    for (int i = 0; i < NLAYER; i++) {
        const float* g  = ln_g + (size_t)i * D_MODEL;
        const float* bb = ln_b + (size_t)i * D_MODEL;

        wpack_kernel<<<(96 * 2304) / 256, 256, 0, stream>>>(w_qkv + i * WQ, wqh, wql, 2304);
        wpack_kernel<<<(96 * 768) / 256, 256, 0, stream>>>(w_proj + i * WP, wph, wpl, 768);
        wpack_kernel<<<(96 * 3072) / 256, 256, 0, stream>>>(w1 + i * W1S, w1h, w1l, 3072);
        wpack_kernel<<<(384 * 768) / 256, 256, 0, stream>>>(w2 + i * W2S, w2h, w2l, 768);

        ln_split_kernel<<<NTOK, 256, 0, stream>>>(i == 0 ? x_in : xw, g, bb, h, hhi, hlo);

        gemm_split<0><<<dim3(64, 18), 256, 0, stream>>>(hhi, hlo, wqh, wql, nullptr, nullptr,
                                                        qkv, nullptr, nullptr, 2304, 768);

        attn_kernel<<<dim3(16, 96), 256, 0, stream>>>(qkv, ohi, olo);

        gemm_split<1><<<dim3(64, 6), 256, 0, stream>>>(ohi, olo, wph, wpl,
                                                       b_proj + (size_t)i * D_MODEL, h,
                                                       xw, nullptr, nullptr, 768, 768);

        ln_split_kernel<<<NTOK, 256, 0, stream>>>(xw, g, bb, h, hhi, hlo);

        gemm_split<2><<<dim3(64, 24), 256, 0, stream>>>(hhi, hlo, w1h, w1l,
                                                        b1 + (size_t)i * MLPDIM, nullptr,
                                                        nullptr, mhi, mlo, 3072, 768);

        float* outp = (i == NLAYER - 1) ? (float*)d_out : xw;
        gemm_split<1><<<dim3(64, 6), 256, 0, stream>>>(mhi, mlo, w2h, w2l,
                                                       b2 + (size_t)i * D_MODEL, h,
                                                       outp, nullptr, nullptr, 768, 3072);
    }
}